// Round 2
// baseline (175.771 us; speedup 1.0000x reference)
//
#include <hip/hip_runtime.h>
#include <hip/hip_bf16.h>

// DynamicWeights fused, single-pass: stage all 64 channels (bf16) in LDS once,
// conv -> softmax -> combine with ONE barrier total.
// x: (8,64,192,192) f32, conv_w: (9,64,3,3) f32, gamma: (1,) f32
// out = gamma * einsum(patches3x3(x), softmax(conv3x3(x,w), k)) + x

constexpr int Nn = 8, Cc = 64, Hh = 192, Ww = 192;
constexpr int TW = 64, TH = 4;          // 256 px tile, 1 px/thread
constexpr int LW = TW + 2;              // 66
constexpr int LH = TH + 2;              // 6

__global__ __launch_bounds__(256, 3)    // 3 waves/EU -> cap VGPR for 3 blocks/CU
void dynw_fused(const float* __restrict__ x, const float* __restrict__ cw,
                const float* __restrict__ gamma, float* __restrict__ out)
{
    // 64*6*66 bf16 = 50688 B -> 3 blocks/CU
    __shared__ __hip_bfloat16 xs[Cc][LH][LW];

    const int tid = threadIdx.x;
    const int tx  = tid & 63;
    const int ty  = tid >> 6;
    const int w0  = blockIdx.x * TW;
    const int h0  = blockIdx.y * TH;
    const int n   = blockIdx.z;

    const float* xn = x + (size_t)n * Cc * Hh * Ww;

    // ---- stage: all channels + halo, coalesced rows, bf16 in LDS ----
#pragma unroll 2
    for (int c = 0; c < Cc; ++c) {
        const float* xc = xn + (size_t)c * Hh * Ww;
#pragma unroll
        for (int t0 = 0; t0 < 2; ++t0) {
            int t = tid + t0 * 256;
            if (t < LH * LW) {
                int r   = t / LW;
                int col = t - r * LW;
                int gh  = h0 + r - 1;
                int gw  = w0 + col - 1;
                float v = 0.f;
                if ((unsigned)gh < (unsigned)Hh && (unsigned)gw < (unsigned)Ww)
                    v = xc[gh * Ww + gw];
                xs[c][r][col] = __float2bfloat16(v);
            }
        }
    }
    __syncthreads();   // the ONLY barrier; xs is read-only below

    // ---- Phase A: conv -> dyn[9] (weights via wave-uniform scalar loads) ----
    float dyn[9];
#pragma unroll
    for (int k = 0; k < 9; ++k) dyn[k] = 0.f;

#pragma unroll 2
    for (int c = 0; c < Cc; ++c) {
        float xv[9];
#pragma unroll
        for (int di = 0; di < 3; ++di)
#pragma unroll
            for (int dj = 0; dj < 3; ++dj)
                xv[di * 3 + dj] = __bfloat162float(xs[c][ty + di][tx + dj]);
        const float* wc = cw + c * 9;
#pragma unroll
        for (int k = 0; k < 9; ++k) {
            const float* wk = wc + (size_t)k * Cc * 9;
#pragma unroll
            for (int p = 0; p < 9; ++p)
                dyn[k] = fmaf(xv[p], wk[p], dyn[k]);
        }
    }

    // ---- softmax over 9 taps (thread-local) ----
    float m = dyn[0];
#pragma unroll
    for (int k = 1; k < 9; ++k) m = fmaxf(m, dyn[k]);
    float f[9];
    float s = 0.f;
#pragma unroll
    for (int k = 0; k < 9; ++k) { f[k] = __expf(dyn[k] - m); s += f[k]; }
    const float inv = 1.0f / s;
#pragma unroll
    for (int k = 0; k < 9; ++k) f[k] *= inv;

    // ---- Phase B: weighted 3x3 combine + residual, from LDS ----
    const float g = gamma[0];
    const int h = h0 + ty, w = w0 + tx;
    float* outn = out + (size_t)n * Cc * Hh * Ww;

#pragma unroll 4
    for (int c = 0; c < Cc; ++c) {
        float acc = 0.f;
        float xcen;
#pragma unroll
        for (int di = 0; di < 3; ++di)
#pragma unroll
            for (int dj = 0; dj < 3; ++dj) {
                float v = __bfloat162float(xs[c][ty + di][tx + dj]);
                if (di == 1 && dj == 1) xcen = v;
                acc = fmaf(v, f[di * 3 + dj], acc);
            }
        outn[((size_t)c * Hh + h) * Ww + w] = fmaf(g, acc, xcen);
    }
}

extern "C" void kernel_launch(void* const* d_in, const int* in_sizes, int n_in,
                              void* d_out, int out_size, void* d_ws, size_t ws_size,
                              hipStream_t stream) {
    const float* x  = (const float*)d_in[0];
    const float* cw = (const float*)d_in[1];
    const float* gm = (const float*)d_in[2];
    float* out = (float*)d_out;

    dim3 grid(Ww / TW, Hh / TH, Nn);   // (3, 48, 8) = 1152 blocks
    dim3 block(256);
    dynw_fused<<<grid, block, 0, stream>>>(x, cw, gm, out);
}